// Round 11
// baseline (2459.446 us; speedup 1.0000x reference)
//
#include <hip/hip_runtime.h>
#include <cstdint>

typedef unsigned short u16;
typedef unsigned int   u32;
typedef float  f32x4  __attribute__((ext_vector_type(4)));
typedef short  short8 __attribute__((ext_vector_type(8)));

__device__ inline float bf2f(u16 b){ u32 u=((u32)b)<<16; float f; __builtin_memcpy(&f,&u,4); return f; }
__device__ inline u16 f2bf(float f){ u32 u; __builtin_memcpy(&u,&f,4); u32 r=u+0x7FFFu+((u>>16)&1u); return (u16)(r>>16); }
// truncating pack (exact when inputs already bf16-valued)
__device__ inline u32 pk(float hi, float lo){ u32 a,b; __builtin_memcpy(&a,&hi,4); __builtin_memcpy(&b,&lo,4); return __builtin_amdgcn_perm(a,b,0x07060302u); }
// RNE pack
__device__ inline u32 pkr(float hi, float lo){ return (u32)f2bf(lo) | ((u32)f2bf(hi)<<16); }
__device__ inline void gload_lds16(const void* g, void* l){
  __builtin_amdgcn_global_load_lds((const __attribute__((address_space(1))) unsigned int*)g,
                                   (__attribute__((address_space(3))) unsigned int*)l, 16, 0, 0);
}

// ---------------------------------------------------------------------------
// prep (unchanged — staged-order weight images):
//  tile t (of 16, 32 k each) = 16384 u16 = 256 lines x 128B.
//  decode of u16 offset o: line=o>>6, w=o&63, slot=w>>3, i=w&7,
//    c8 = slot ^ (line&7), n = 2*line + (c8>>2), g = c8&3.
//  Wt_in3 value = bf16(W_in[k][n]),  k = t*32 + g*8 + i      (linear k)
//  Wt_hd3 value = bf16(W_head[k][n]), k = t*32 + sigma(g,i)  (sigma-permuted)
//  gw1f: S-MFMA B-frags [8d][16c][4g][5col][8i] (2560/depth)
//  updA: update A-frags [8d][32t][16m][8sl]     (4096/depth)
// ---------------------------------------------------------------------------
__global__ __launch_bounds__(256) void prep_k(
    const float* __restrict__ W_in, const float* __restrict__ W_head,
    const float* __restrict__ ln_g, const float* __restrict__ W1,
    const float* __restrict__ W2, const float* __restrict__ b2,
    u16* __restrict__ Wt_in3, u16* __restrict__ Wt_hd3,
    u16* __restrict__ gw1f, u16* __restrict__ updA)
{
  int idx = blockIdx.x * 256 + threadIdx.x;
  if (idx < 524288){
    int which = idx >> 18;            // 0: W_in, 1: W_head
    int q = idx & 262143;
    int t = q >> 14, o = q & 16383;
    int line = o >> 6, w = o & 63, slot = w >> 3, i = w & 7;
    int c8 = slot ^ (line & 7);
    int n = 2 * line + (c8 >> 2);
    int g = c8 & 3;
    if (which == 0){
      int k = t * 32 + g * 8 + i;
      Wt_in3[q] = f2bf(W_in[k * 512 + n]);
    } else {
      int k = t * 32 + (i < 4 ? 4 * g + i : 12 + 4 * g + i);
      Wt_hd3[q] = f2bf(W_head[k * 512 + n]);
    }
  } else if (idx < 544768){
    int q = idx - 524288;                 // 8*2560
    int d = q / 2560, r = q % 2560;
    int c = r / 160, r2 = r % 160;
    int g = r2 / 40, r3 = r2 % 40;
    int col = r3 >> 3, i = r3 & 7;
    int k = 32 * c + (i < 4 ? 4 * g + i : 12 + 4 * g + i);
    u16 v;
    if (col == 4) v = 0x3F80u;
    else          v = f2bf(ln_g[d * 512 + k] * W1[(d * 512 + k) * 4 + col]);
    gw1f[q] = v;
  } else if (idx < 577536){
    int q = idx - 544768;                 // 8*4096
    int d = q >> 12, r = q & 4095;
    int t = r >> 7, r2 = r & 127;
    int m = r2 >> 3, sl = r2 & 7;
    int k = 16 * t + m;
    u16 v = 0;
    if (sl < 4)       v = f2bf(W2[(d * 4 + sl) * 512 + k]);
    else if (sl == 4) v = f2bf(b2[d * 512 + k]);
    updA[q] = v;
  }
}

// U[d][e] = sum_k bf16(g*W1); V = sum ln_b*W1 + b1
__global__ __launch_bounds__(64) void uv_k(
    const float* __restrict__ ln_g, const float* __restrict__ ln_b,
    const float* __restrict__ W1, const float* __restrict__ b1,
    float* __restrict__ U, float* __restrict__ V)
{
  int d = blockIdx.x >> 2, e = blockIdx.x & 3;
  int lane = threadIdx.x;
  float u = 0.f, v = 0.f;
  for (int k = lane; k < 512; k += 64){
    float w = W1[(d * 512 + k) * 4 + e];
    u += bf2f(f2bf(ln_g[d * 512 + k] * w));
    v += ln_b[d * 512 + k] * w;
  }
  for (int m = 1; m < 64; m <<= 1){ u += __shfl_xor(u, m); v += __shfl_xor(v, m); }
  if (lane == 0){ U[d * 4 + e] = u; V[d * 4 + e] = v + b1[d * 4 + e]; }
}

// ---------------------------------------------------------------------------
// fused v6: 64 rows/block, 8 waves (512 thr), wave = (qh = wv>>2, nq = wv&3).
// = r9's v5 with (a) the t==15 stageM race removed (stageM(0,0) now sits
// behind phase A's final barrier — the bug that corrupted r9), and (b) x
// prefetched one t-step ahead (xr regs) so HBM latency is off the critical
// path. Per-thread live state ~115 regs -> (512,4) cap 128 w/o spill;
// LDS 75776 (74K) -> 2 blocks/CU, 16 waves/CU.
// hv[ql][c2][half][r] = h[row = qh*32+ql*16+m][k = nq*128 + c2*32 + half*16 + 4g+r]
// LDS regions:
//   [0,64K)        A/C weight dbuf (2x32K)
//   [32K,59392)    mid weight dbuf (2x13312)   [mid only; overlays weight buf1]
//   [59392,65536)  sS partials [4qg][4nq][6][16] f32 (6K)  [mid only]
//   [64K,73728)    hx h-broadcast (2x4K), slot = lane*16   [phase C only]
//   [73728,75024)  zbuf(1K) + sUV(256B) + sZ(16B)          [mid only]
// Race audit: every gload_lds destination region is disjoint from all LDS
// ranges readable between its issue-barrier and its drain-barrier.
// ---------------------------------------------------------------------------
__global__ __launch_bounds__(512, 4) void fused_k(
    const float* __restrict__ x, const u16* __restrict__ Wt_in3,
    const float* __restrict__ b_in, const u16* __restrict__ Wt_hd3,
    const float* __restrict__ b_head, const u16* __restrict__ gw1f,
    const u16* __restrict__ updA, const float* __restrict__ U,
    const float* __restrict__ V, float* __restrict__ out)
{
  __shared__ __align__(16) char LT[75776];
  constexpr int MB  = 32768;     // mid dbuf base (stride 13312)
  constexpr int SSo = 59392;     // partials
  constexpr int HX  = 65536;     // h broadcast dbuf (2 x 4096)
  constexpr int ZBo = 73728, UVo = 74752, SZo = 75008;
  float* sSf = (float*)(LT + SSo);
  float* zbf = (float*)(LT + ZBo);
  float* sUV = (float*)(LT + UVo);
  u16*   sZ  = (u16*)(LT + SZo);

  const int tid  = threadIdx.x;
  const int wv   = tid >> 6;
  const int lane = tid & 63;
  const int m    = lane & 15;
  const int g    = lane >> 4;
  const int nq   = wv & 3;
  const int qh   = wv >> 2;
  const size_t rowbase = (size_t)blockIdx.x * 64;

  if (tid < 32) sUV[tid] = U[tid];
  else if (tid < 64) sUV[tid] = V[tid - 32];
  if (tid >= 64 && tid < 72) sZ[tid - 64] = 0;

  auto stageA = [&](const u16* W, int t, char* dst){
    const char* src = (const char*)(W + t * 16384) + tid * 16;
    char* d2 = dst + tid * 16;
    #pragma unroll
    for (int j = 0; j < 4; ++j)
      gload_lds16(src + j * 8192, d2 + j * 8192);
  };
  auto stageM = [&](int d, int bf2){
    char* dsg = LT + MB + bf2 * 13312;
    if (tid < 320)
      gload_lds16((const char*)gw1f + d * 5120 + tid * 16, dsg + tid * 16);
    gload_lds16((const char*)updA + d * 8192 + tid * 16, dsg + 5120 + tid * 16);
  };

  auto mkfrag = [&](f32x4 a, f32x4 b)->short8{     // RNE
    union{u32 u[4]; short8 s;} t;
    t.u[0]=pkr(a[1],a[0]); t.u[1]=pkr(a[3],a[2]);
    t.u[2]=pkr(b[1],b[0]); t.u[3]=pkr(b[3],b[2]);
    return t.s;
  };
  auto mkfragT = [&](f32x4 a, f32x4 b)->short8{    // trunc (h already bf16-valued)
    union{u32 u[4]; short8 s;} t;
    t.u[0]=pk(a[1],a[0]); t.u[1]=pk(a[3],a[2]);
    t.u[2]=pk(b[1],b[0]); t.u[3]=pk(b[3],b[2]);
    return t.s;
  };

  // A-frag byte base inside a staged tile (conflict-light pattern)
  const int afoff = (m >> 1) * 128 + (((((m & 1) << 2) | g) ^ ((m >> 1) & 7)) << 4);

  // ================= phase A: h = relu(x @ W_in + b_in) =================
  f32x4 hv[2][4][2];
  #pragma unroll
  for (int ql = 0; ql < 2; ++ql)
    #pragma unroll
    for (int c2 = 0; c2 < 4; ++c2){ hv[ql][c2][0] = (f32x4)0.f; hv[ql][c2][1] = (f32x4)0.f; }

  const float* xbase = x + (rowbase + qh * 32 + m) * 512 + g * 8;
  f32x4 xr[2][2];
  xr[0][0] = *(const f32x4*)(xbase);
  xr[0][1] = *(const f32x4*)(xbase + 4);
  xr[1][0] = *(const f32x4*)(xbase + 8192);
  xr[1][1] = *(const f32x4*)(xbase + 8192 + 4);
  stageA(Wt_in3, 0, LT);
  __syncthreads();

  #pragma unroll 2
  for (int t = 0; t < 16; ++t){
    const int pb = t & 1;
    if (t < 15) stageA(Wt_in3, t + 1, LT + ((t + 1) & 1) * 32768);
    short8 bq[2];
    bq[0] = mkfrag(xr[0][0], xr[0][1]);
    bq[1] = mkfrag(xr[1][0], xr[1][1]);
    if (t < 15){
      xr[0][0] = *(const f32x4*)(xbase + (t + 1) * 32);
      xr[0][1] = *(const f32x4*)(xbase + (t + 1) * 32 + 4);
      xr[1][0] = *(const f32x4*)(xbase + 8192 + (t + 1) * 32);
      xr[1][1] = *(const f32x4*)(xbase + 8192 + (t + 1) * 32 + 4);
    }
    const char* wb = LT + pb * 32768 + nq * 8192 + afoff;
    #pragma unroll
    for (int f = 0; f < 8; ++f){
      short8 aw = *(const short8*)(wb + f * 1024);
      #pragma unroll
      for (int ql = 0; ql < 2; ++ql)
        hv[ql][f >> 1][f & 1] =
          __builtin_amdgcn_mfma_f32_16x16x32_bf16(aw, bq[ql], hv[ql][f >> 1][f & 1], 0, 0, 0);
    }
    __syncthreads();
  }

  // epilogue: +bias, relu, round to bf16 values
  #pragma unroll
  for (int ql = 0; ql < 2; ++ql)
    #pragma unroll
    for (int c2 = 0; c2 < 4; ++c2)
      #pragma unroll
      for (int hf = 0; hf < 2; ++hf){
        f32x4 bi = *(const f32x4*)(b_in + nq * 128 + c2 * 32 + hf * 16 + g * 4);
        #pragma unroll
        for (int r = 0; r < 4; ++r){
          float v = hv[ql][c2][hf][r] + bi[r];
          v = v > 0.f ? v : 0.f;
          hv[ql][c2][hf][r] = bf2f(f2bf(v));
        }
      }

  // stage first mid depth BEHIND its own barrier (r9's race removed: nothing
  // may read [32768,46080) while these loads are in flight)
  stageM(0, 0);
  __syncthreads();

  // ================= mid: 8 residual MLP blocks (n-split) =================
  int buf = 0;
  #pragma unroll 1
  for (int d = 0; d < 8; ++d){
    if (d < 7) stageM(d + 1, buf ^ 1);
    else       stageA(Wt_hd3, 0, LT);          // prefetch C chunk 0 into [0,32K) (mid never reads it)

    const u16* sGp = (const u16*)(LT + MB + buf * 13312);
    const u16* sAp = sGp + 2560;

    // ---- per-slice S + sum(ones col) + Gram(sumsq)
    const u16* gb = (m < 5) ? (sGp + nq * 640 + g * 40 + m * 8) : sZ;
    const int gstep = (m < 5) ? 160 : 0;
    f32x4 aS[2] = {{0.f,0.f,0.f,0.f},{0.f,0.f,0.f,0.f}};
    f32x4 aG[2] = {{0.f,0.f,0.f,0.f},{0.f,0.f,0.f,0.f}};
    #pragma unroll
    for (int c2 = 0; c2 < 4; ++c2){
      short8 bf = *(const short8*)(gb + c2 * gstep);
      #pragma unroll
      for (int ql = 0; ql < 2; ++ql){
        short8 af = mkfragT(hv[ql][c2][0], hv[ql][c2][1]);
        aS[ql] = __builtin_amdgcn_mfma_f32_16x16x32_bf16(af, bf, aS[ql], 0, 0, 0);
        aG[ql] = __builtin_amdgcn_mfma_f32_16x16x32_bf16(af, af, aG[ql], 0, 0, 0);
      }
    }

    // ---- write per-slice partials: [qg][nq][e=0..5][16 batch]
    #pragma unroll
    for (int ql = 0; ql < 2; ++ql){
      const int qg = qh * 2 + ql;
      if (m < 5)
        *(f32x4*)(sSf + ((qg * 4 + nq) * 6 + m) * 16 + 4 * g) = aS[ql];
      if ((m >> 2) == g)
        sSf[((qg * 4 + nq) * 6 + 5) * 16 + m] = aG[ql][m & 3];
    }
    __syncthreads();

    // ---- z for all 64 rows (threads 0..63)
    if (tid < 64){
      int qg2 = tid >> 4, b = tid & 15;
      float S0 = 0.f, S1 = 0.f, S2 = 0.f, S3 = 0.f, sm = 0.f, sq = 0.f;
      #pragma unroll
      for (int nn = 0; nn < 4; ++nn){
        const float* pp = sSf + ((qg2 * 4 + nn) * 6) * 16 + b;
        S0 += pp[0]; S1 += pp[16]; S2 += pp[32]; S3 += pp[48];
        sm += pp[64]; sq += pp[80];
      }
      float mu  = sm * (1.f / 512.f);
      float var = sq * (1.f / 512.f) - mu * mu;
      float rs  = rsqrtf(var + 1e-5f);
      f32x4 zz;
      float z0 = fmaf(rs, S0 - mu * sUV[d * 4 + 0], sUV[32 + d * 4 + 0]);
      float z1 = fmaf(rs, S1 - mu * sUV[d * 4 + 1], sUV[32 + d * 4 + 1]);
      float z2 = fmaf(rs, S2 - mu * sUV[d * 4 + 2], sUV[32 + d * 4 + 2]);
      float z3 = fmaf(rs, S3 - mu * sUV[d * 4 + 3], sUV[32 + d * 4 + 3]);
      zz[0] = z0 > 0.f ? z0 : 0.f;
      zz[1] = z1 > 0.f ? z1 : 0.f;
      zz[2] = z2 > 0.f ? z2 : 0.f;
      zz[3] = z3 > 0.f ? z3 : 0.f;
      *(f32x4*)(zbf + tid * 4) = zz;
    }
    __syncthreads();

    // ---- update: h += [W2|b2]^T [z|1] on own k-slice
    #pragma unroll
    for (int ql = 0; ql < 2; ++ql){
      f32x4 z4 = *(const f32x4*)(zbf + (qh * 32 + ql * 16 + m) * 4);
      union{u32 u[4]; short8 s;} bz;
      bz.u[0] = (g == 0) ? pk(z4[1], z4[0]) : 0u;
      bz.u[1] = (g == 0) ? pk(z4[3], z4[2]) : 0u;
      bz.u[2] = (g == 0) ? 0x00003F80u : 0u;
      bz.u[3] = 0u;
      const u16* ab = (g == 0) ? (sAp + nq * 1024 + m * 8) : sZ;
      const int ainc = (g == 0) ? 128 : 0;
      #pragma unroll
      for (int t2 = 0; t2 < 8; ++t2){
        short8 aw = *(const short8*)(ab + t2 * ainc);
        hv[ql][t2 >> 1][t2 & 1] =
          __builtin_amdgcn_mfma_f32_16x16x32_bf16(aw, bz.s, hv[ql][t2 >> 1][t2 & 1], 0, 0, 0);
      }
    }
    __syncthreads();
    buf ^= 1;
  }

  // ================= phase C: out = h @ W_head + b_head ===================
  // pack h (RNE — pipeline's h rounding); hv dead afterwards
  short8 p[2][4];
  #pragma unroll
  for (int ql = 0; ql < 2; ++ql)
    #pragma unroll
    for (int c2 = 0; c2 < 4; ++c2)
      p[ql][c2] = mkfrag(hv[ql][c2][0], hv[ql][c2][1]);

  f32x4 acc[2][8];
  #pragma unroll
  for (int ql = 0; ql < 2; ++ql)
    #pragma unroll
    for (int of = 0; of < 8; ++of) acc[ql][of] = (f32x4)0.f;

  // broadcast chunk 0 (owner nq==0); hx slot = lane*16 (conflict-free)
  if (nq == 0){
    #pragma unroll
    for (int ql = 0; ql < 2; ++ql)
      *(short8*)(LT + HX + qh * 2048 + ql * 1024 + lane * 16) = p[ql][0];
  }
  __syncthreads();

  #pragma unroll 4
  for (int c = 0; c < 16; ++c){
    if (c < 15){
      stageA(Wt_hd3, c + 1, LT + ((c + 1) & 1) * 32768);
      if (nq == ((c + 1) >> 2)){
        #pragma unroll
        for (int ql = 0; ql < 2; ++ql)
          *(short8*)(LT + HX + ((c + 1) & 1) * 4096 + qh * 2048 + ql * 1024 + lane * 16)
            = p[ql][(c + 1) & 3];
      }
    }
    const char* hxb = LT + HX + (c & 1) * 4096 + qh * 2048 + lane * 16;
    short8 bh0 = *(const short8*)(hxb);
    short8 bh1 = *(const short8*)(hxb + 1024);
    const char* wb = LT + (c & 1) * 32768 + nq * 8192 + afoff;
    #pragma unroll
    for (int of = 0; of < 8; ++of){
      short8 aw = *(const short8*)(wb + of * 1024);
      acc[0][of] = __builtin_amdgcn_mfma_f32_16x16x32_bf16(aw, bh0, acc[0][of], 0, 0, 0);
      acc[1][of] = __builtin_amdgcn_mfma_f32_16x16x32_bf16(aw, bh1, acc[1][of], 0, 0, 0);
    }
    __syncthreads();
  }

  // epilogue: +bias, store
  #pragma unroll
  for (int ql = 0; ql < 2; ++ql)
    #pragma unroll
    for (int of = 0; of < 8; ++of){
      f32x4 bhd = *(const f32x4*)(b_head + nq * 128 + of * 16 + g * 4);
      f32x4 v;
      #pragma unroll
      for (int r = 0; r < 4; ++r) v[r] = acc[ql][of][r] + bhd[r];
      *(f32x4*)(out + (rowbase + qh * 32 + ql * 16 + m) * 512 + nq * 128 + of * 16 + g * 4) = v;
    }
}

// ---------------------------------------------------------------------------
extern "C" void kernel_launch(void* const* d_in, const int* in_sizes, int n_in,
                              void* d_out, int out_size, void* d_ws, size_t ws_size,
                              hipStream_t stream)
{
  const float* x      = (const float*)d_in[0];
  const float* W_in   = (const float*)d_in[1];
  const float* b_in   = (const float*)d_in[2];
  const float* ln_g   = (const float*)d_in[3];
  const float* ln_b   = (const float*)d_in[4];
  const float* W1     = (const float*)d_in[5];
  const float* b1     = (const float*)d_in[6];
  const float* W2     = (const float*)d_in[7];
  const float* b2     = (const float*)d_in[8];
  const float* W_head = (const float*)d_in[9];
  const float* b_head = (const float*)d_in[10];
  float* out = (float*)d_out;
  const int B = in_sizes[0] / 512;

  char* ws = (char*)d_ws;
  u16*   Wt_in3 = (u16*)ws;                 // 262144
  u16*   Wt_hd3 = Wt_in3 + 262144;          // 262144
  u16*   gw1f   = Wt_hd3 + 262144;          // 20480
  u16*   updA   = gw1f + 20480;             // 32768
  float* Up     = (float*)(updA + 32768);   // 32
  float* Vp     = Up + 32;                  // 32

  prep_k<<<2256, 256, 0, stream>>>(W_in, W_head, ln_g, W1, W2, b2, Wt_in3, Wt_hd3, gw1f, updA);
  uv_k<<<32, 64, 0, stream>>>(ln_g, ln_b, W1, b1, Up, Vp);
  fused_k<<<B / 64, 512, 0, stream>>>(x, Wt_in3, b_in, Wt_hd3, b_head, gw1f, updA, Up, Vp, out);
}

// Round 12
// 365.044 us; speedup vs baseline: 6.7374x; 6.7374x over previous
//
#include <hip/hip_runtime.h>
#include <cstdint>

typedef unsigned short u16;
typedef unsigned int   u32;
typedef float  f32x4  __attribute__((ext_vector_type(4)));
typedef short  short8 __attribute__((ext_vector_type(8)));

__device__ inline float bf2f(u16 b){ u32 u=((u32)b)<<16; float f; __builtin_memcpy(&f,&u,4); return f; }
__device__ inline u16 f2bf(float f){ u32 u; __builtin_memcpy(&u,&f,4); u32 r=u+0x7FFFu+((u>>16)&1u); return (u16)(r>>16); }
// truncating pack (exact when inputs already bf16-valued)
__device__ inline u32 pk(float hi, float lo){ u32 a,b; __builtin_memcpy(&a,&hi,4); __builtin_memcpy(&b,&lo,4); return __builtin_amdgcn_perm(a,b,0x07060302u); }
// RNE pack
__device__ inline u32 pkr(float hi, float lo){ return (u32)f2bf(lo) | ((u32)f2bf(hi)<<16); }
__device__ inline void gload_lds16(const void* g, void* l){
  __builtin_amdgcn_global_load_lds((const __attribute__((address_space(1))) unsigned int*)g,
                                   (__attribute__((address_space(3))) unsigned int*)l, 16, 0, 0);
}

// counted-vmcnt barrier (T4): wait own older loads, keep newest K in flight,
// then barrier. sched_barrier(0) pins: nothing (esp. next stage/ds_read) may
// be hoisted above the s_barrier.
#define CBAR(K) do{ asm volatile("s_waitcnt vmcnt(" #K ") lgkmcnt(0)" ::: "memory"); \
  __builtin_amdgcn_s_barrier(); __builtin_amdgcn_sched_barrier(0); }while(0)

// ---------------------------------------------------------------------------
// prep (unchanged — staged-order weight images):
//  tile t (of 16, 32 k each) = 16384 u16 = 256 lines x 128B.
//  decode of u16 offset o: line=o>>6, w=o&63, slot=w>>3, i=w&7,
//    c8 = slot ^ (line&7), n = 2*line + (c8>>2), g = c8&3.
//  Wt_in3 value = bf16(W_in[k][n]),  k = t*32 + g*8 + i      (linear k)
//  Wt_hd3 value = bf16(W_head[k][n]), k = t*32 + sigma(g,i)  (sigma-permuted)
//  gw1f: S-MFMA B-frags [8d][16c][4g][5col][8i] (2560/depth)
//  updA: update A-frags [8d][32t][16m][8sl]     (4096/depth)
// ---------------------------------------------------------------------------
__global__ __launch_bounds__(256) void prep_k(
    const float* __restrict__ W_in, const float* __restrict__ W_head,
    const float* __restrict__ ln_g, const float* __restrict__ W1,
    const float* __restrict__ W2, const float* __restrict__ b2,
    u16* __restrict__ Wt_in3, u16* __restrict__ Wt_hd3,
    u16* __restrict__ gw1f, u16* __restrict__ updA)
{
  int idx = blockIdx.x * 256 + threadIdx.x;
  if (idx < 524288){
    int which = idx >> 18;            // 0: W_in, 1: W_head
    int q = idx & 262143;
    int t = q >> 14, o = q & 16383;
    int line = o >> 6, w = o & 63, slot = w >> 3, i = w & 7;
    int c8 = slot ^ (line & 7);
    int n = 2 * line + (c8 >> 2);
    int g = c8 & 3;
    if (which == 0){
      int k = t * 32 + g * 8 + i;
      Wt_in3[q] = f2bf(W_in[k * 512 + n]);
    } else {
      int k = t * 32 + (i < 4 ? 4 * g + i : 12 + 4 * g + i);
      Wt_hd3[q] = f2bf(W_head[k * 512 + n]);
    }
  } else if (idx < 544768){
    int q = idx - 524288;                 // 8*2560
    int d = q / 2560, r = q % 2560;
    int c = r / 160, r2 = r % 160;
    int g = r2 / 40, r3 = r2 % 40;
    int col = r3 >> 3, i = r3 & 7;
    int k = 32 * c + (i < 4 ? 4 * g + i : 12 + 4 * g + i);
    u16 v;
    if (col == 4) v = 0x3F80u;
    else          v = f2bf(ln_g[d * 512 + k] * W1[(d * 512 + k) * 4 + col]);
    gw1f[q] = v;
  } else if (idx < 577536){
    int q = idx - 544768;                 // 8*4096
    int d = q >> 12, r = q & 4095;
    int t = r >> 7, r2 = r & 127;
    int m = r2 >> 3, sl = r2 & 7;
    int k = 16 * t + m;
    u16 v = 0;
    if (sl < 4)       v = f2bf(W2[(d * 4 + sl) * 512 + k]);
    else if (sl == 4) v = f2bf(b2[d * 512 + k]);
    updA[q] = v;
  }
}

// U[d][e] = sum_k bf16(g*W1); V = sum ln_b*W1 + b1
__global__ __launch_bounds__(64) void uv_k(
    const float* __restrict__ ln_g, const float* __restrict__ ln_b,
    const float* __restrict__ W1, const float* __restrict__ b1,
    float* __restrict__ U, float* __restrict__ V)
{
  int d = blockIdx.x >> 2, e = blockIdx.x & 3;
  int lane = threadIdx.x;
  float u = 0.f, v = 0.f;
  for (int k = lane; k < 512; k += 64){
    float w = W1[(d * 512 + k) * 4 + e];
    u += bf2f(f2bf(ln_g[d * 512 + k] * w));
    v += ln_b[d * 512 + k] * w;
  }
  for (int m = 1; m < 64; m <<= 1){ u += __shfl_xor(u, m); v += __shfl_xor(v, m); }
  if (lane == 0){ U[d * 4 + e] = u; V[d * 4 + e] = v + b1[d * 4 + e]; }
}

// ---------------------------------------------------------------------------
// fused v7: v2 geometry (128 rows/block, 8 waves, nq/rh decomposition,
// (512,2), 1 block/CU) + counted-vmcnt pipeline in phases A/C:
//   - weight tiles triple-buffered (tb0/1/2), staged 2 steps ahead
//   - x prefetched 2 bodies ahead (xA/xB ping-pong regs)
//   - barriers = CBAR(K): keep the intentional in-flight prefetch, drain only
//     what the next body reads. K derivation in comments.
// Mid (8 depths) is v2 verbatim (full __syncthreads; L2-short drains).
// LDS (131344 B, no live-range overlap):
//   [0,98304)        tb0/1/2 weight tiles (A and C)
//   [65536,77824)    sS partials  [mid only; tb2 dead during mid]
//   [77824,79872)    zbuf         [mid only; in tb2]
//   [98304,131072)   mid dbuf 2x16384 (gw1f 5120 + updA 8192) [mid only]
//   [98304,114688)   hx h-broadcast 2x8192 [phase C only; mid dbuf dead]
//   [131072,131344)  sUV + sZ (persistent)
// hv[q][c2][half][r] = h[row=rh*64+q*16+m][k=nq*128+c2*32+half*16+4g+r]
// ---------------------------------------------------------------------------
__global__ __launch_bounds__(512, 2) void fused_k(
    const float* __restrict__ x, const u16* __restrict__ Wt_in3,
    const float* __restrict__ b_in, const u16* __restrict__ Wt_hd3,
    const float* __restrict__ b_head, const u16* __restrict__ gw1f,
    const u16* __restrict__ updA, const float* __restrict__ U,
    const float* __restrict__ V, float* __restrict__ out)
{
  __shared__ __align__(16) char LT[131344];
  constexpr int SSo = 65536, ZBo = 77824;
  constexpr int MIDB = 98304, HXo = 98304;
  constexpr int UVo = 131072, SZo = 131328;
  float* sSf = (float*)(LT + SSo);
  float* zbf = (float*)(LT + ZBo);
  float* sUV = (float*)(LT + UVo);
  u16*   sZ  = (u16*)(LT + SZo);

  const int tid  = threadIdx.x;
  const int wv   = tid >> 6;
  const int lane = tid & 63;
  const int m    = lane & 15;
  const int g    = lane >> 4;
  const int nq   = wv & 3;
  const int rh   = wv >> 2;
  const size_t rowbase = (size_t)blockIdx.x * 128 + rh * 64;

  if (tid < 32) sUV[tid] = U[tid];
  else if (tid < 64) sUV[tid] = V[tid - 32];
  if (tid >= 64 && tid < 72) sZ[tid - 64] = 0;

  auto stageA = [&](const u16* W, int t, char* dst){
    const char* src = (const char*)(W + t * 16384) + tid * 16;
    char* d2 = dst + tid * 16;
    #pragma unroll
    for (int j = 0; j < 4; ++j)
      gload_lds16(src + j * 8192, d2 + j * 8192);
  };
  auto stageM = [&](int d, int bf2){
    char* dsg = LT + MIDB + bf2 * 16384;
    if (tid < 320)
      gload_lds16((const char*)gw1f + d * 5120 + tid * 16, dsg + tid * 16);
    gload_lds16((const char*)updA + d * 8192 + tid * 16, dsg + 5120 + tid * 16);
  };

  auto mkfrag = [&](f32x4 a, f32x4 b)->short8{     // RNE
    union{u32 u[4]; short8 s;} t;
    t.u[0]=pkr(a[1],a[0]); t.u[1]=pkr(a[3],a[2]);
    t.u[2]=pkr(b[1],b[0]); t.u[3]=pkr(b[3],b[2]);
    return t.s;
  };
  auto mkfragT = [&](f32x4 a, f32x4 b)->short8{    // trunc (h already bf16-valued)
    union{u32 u[4]; short8 s;} t;
    t.u[0]=pk(a[1],a[0]); t.u[1]=pk(a[3],a[2]);
    t.u[2]=pk(b[1],b[0]); t.u[3]=pk(b[3],b[2]);
    return t.s;
  };

  // A-frag byte base inside a staged tile (conflict-light pattern)
  const int afoff = (m >> 1) * 128 + (((((m & 1) << 2) | g) ^ ((m >> 1) & 7)) << 4);

  // ================= phase A: h = relu(x @ W_in + b_in) =================
  f32x4 hv[4][4][2];
  #pragma unroll
  for (int q = 0; q < 4; ++q)
    #pragma unroll
    for (int c2 = 0; c2 < 4; ++c2){ hv[q][c2][0] = (f32x4)0.f; hv[q][c2][1] = (f32x4)0.f; }

  const float* xbase = x + (rowbase + m) * 512 + g * 8;
  f32x4 xA[4][2], xB[4][2];
  #pragma unroll
  for (int q = 0; q < 4; ++q){
    xA[q][0] = *(const f32x4*)(xbase + q * 8192);
    xA[q][1] = *(const f32x4*)(xbase + q * 8192 + 4);
    xB[q][0] = *(const f32x4*)(xbase + q * 8192 + 32);
    xB[q][1] = *(const f32x4*)(xbase + q * 8192 + 36);
  }
  stageA(Wt_in3, 0, LT);
  stageA(Wt_in3, 1, LT + 32768);
  __syncthreads();

  // Body t: stage(t+2)[4 loads] ; bq=mkfrag(x(t)) [compiler-waited, 2 bodies
  // of latency] ; reload same x regs with x(t+2)[8 loads] ; 32 MFMA on
  // tb[t%3] ; CBAR. Steady K=20 keeps {stage(t+2),x(t+1),x(t+2)} and drains
  // stage(t+1) (read next body). t=14: K=8 keeps x(15), drains stage(15).
  // t=15: no barrier (epilogue is register-only; full sync before mid).
  #pragma unroll
  for (int t = 0; t < 16; ++t){
    if (t < 14) stageA(Wt_in3, t + 2, LT + ((t + 2) % 3) * 32768);
    short8 bq[4];
    #pragma unroll
    for (int q = 0; q < 4; ++q)
      bq[q] = (t & 1) ? mkfrag(xB[q][0], xB[q][1]) : mkfrag(xA[q][0], xA[q][1]);
    if (t < 14){
      #pragma unroll
      for (int q = 0; q < 4; ++q){
        if (t & 1){
          xB[q][0] = *(const f32x4*)(xbase + q * 8192 + (t + 2) * 32);
          xB[q][1] = *(const f32x4*)(xbase + q * 8192 + (t + 2) * 32 + 4);
        } else {
          xA[q][0] = *(const f32x4*)(xbase + q * 8192 + (t + 2) * 32);
          xA[q][1] = *(const f32x4*)(xbase + q * 8192 + (t + 2) * 32 + 4);
        }
      }
    }
    const char* wb = LT + (t % 3) * 32768 + nq * 8192 + afoff;
    #pragma unroll
    for (int f = 0; f < 8; ++f){
      short8 aw = *(const short8*)(wb + f * 1024);
      #pragma unroll
      for (int q = 0; q < 4; ++q)
        hv[q][f >> 1][f & 1] =
          __builtin_amdgcn_mfma_f32_16x16x32_bf16(aw, bq[q], hv[q][f >> 1][f & 1], 0, 0, 0);
    }
    if (t < 14)       CBAR(20);
    else if (t == 14) CBAR(8);
  }

  // epilogue: +bias, relu, round to bf16 values
  #pragma unroll
  for (int q = 0; q < 4; ++q)
    #pragma unroll
    for (int c2 = 0; c2 < 4; ++c2)
      #pragma unroll
      for (int hf = 0; hf < 2; ++hf){
        f32x4 bi = *(const f32x4*)(b_in + nq * 128 + c2 * 32 + hf * 16 + g * 4);
        #pragma unroll
        for (int r = 0; r < 4; ++r){
          float v = hv[q][c2][hf][r] + bi[r];
          v = v > 0.f ? v : 0.f;
          hv[q][c2][hf][r] = bf2f(f2bf(v));
        }
      }

  // ================= mid: 8 residual MLP blocks (v2 verbatim) =============
  stageM(0, 0);
  __syncthreads();
  int buf = 0;
  #pragma unroll 1
  for (int d = 0; d < 8; ++d){
    if (d < 7) stageM(d + 1, buf ^ 1);
    else       stageA(Wt_hd3, 0, LT);          // prefetch C tile 0 into tb0

    const u16* sGp = (const u16*)(LT + MIDB + buf * 16384);
    const u16* sAp = sGp + 2560;

    // ---- per-slice S + sum(ones col) + Gram(sumsq), 4 row-groups
    const u16* gb = (m < 5) ? (sGp + nq * 640 + g * 40 + m * 8) : sZ;
    const int gstep = (m < 5) ? 160 : 0;
    f32x4 aS[4], aG[4];
    #pragma unroll
    for (int q = 0; q < 4; ++q){ aS[q] = (f32x4)0.f; aG[q] = (f32x4)0.f; }
    #pragma unroll
    for (int c2 = 0; c2 < 4; ++c2){
      short8 bf = *(const short8*)(gb + c2 * gstep);
      #pragma unroll
      for (int q = 0; q < 4; ++q){
        short8 af = mkfragT(hv[q][c2][0], hv[q][c2][1]);
        aS[q] = __builtin_amdgcn_mfma_f32_16x16x32_bf16(af, bf, aS[q], 0, 0, 0);
        aG[q] = __builtin_amdgcn_mfma_f32_16x16x32_bf16(af, af, aG[q], 0, 0, 0);
      }
    }

    // ---- write per-slice partials: [rh][q][nq][e=0..5][16 batch]
    #pragma unroll
    for (int q = 0; q < 4; ++q){
      if (m < 5)
        *(f32x4*)(sSf + (((rh * 4 + q) * 4 + nq) * 6 + m) * 16 + 4 * g) = aS[q];
      if ((m >> 2) == g)
        sSf[(((rh * 4 + q) * 4 + nq) * 6 + 5) * 16 + m] = aG[q][m & 3];
    }
    __syncthreads();

    // ---- z for all 128 rows (threads 0..127)
    if (tid < 128){
      int rh2 = tid >> 6, rl = tid & 63, q2 = rl >> 4, b = rl & 15;
      float S0 = 0.f, S1 = 0.f, S2 = 0.f, S3 = 0.f, sm = 0.f, sq = 0.f;
      #pragma unroll
      for (int nn = 0; nn < 4; ++nn){
        const float* pp = sSf + (((rh2 * 4 + q2) * 4 + nn) * 6) * 16 + b;
        S0 += pp[0]; S1 += pp[16]; S2 += pp[32]; S3 += pp[48];
        sm += pp[64]; sq += pp[80];
      }
      float mu  = sm * (1.f / 512.f);
      float var = sq * (1.f / 512.f) - mu * mu;
      float rs  = rsqrtf(var + 1e-5f);
      f32x4 zz;
      float z0 = fmaf(rs, S0 - mu * sUV[d * 4 + 0], sUV[32 + d * 4 + 0]);
      float z1 = fmaf(rs, S1 - mu * sUV[d * 4 + 1], sUV[32 + d * 4 + 1]);
      float z2 = fmaf(rs, S2 - mu * sUV[d * 4 + 2], sUV[32 + d * 4 + 2]);
      float z3 = fmaf(rs, S3 - mu * sUV[d * 4 + 3], sUV[32 + d * 4 + 3]);
      zz[0] = z0 > 0.f ? z0 : 0.f;
      zz[1] = z1 > 0.f ? z1 : 0.f;
      zz[2] = z2 > 0.f ? z2 : 0.f;
      zz[3] = z3 > 0.f ? z3 : 0.f;
      *(f32x4*)(zbf + tid * 4) = zz;
    }
    __syncthreads();

    // ---- update: h += [W2|b2]^T [z|1] on own k-slice
    #pragma unroll
    for (int q = 0; q < 4; ++q){
      f32x4 z4 = *(const f32x4*)(zbf + (rh * 64 + q * 16 + m) * 4);
      union{u32 u[4]; short8 s;} bz;
      bz.u[0] = (g == 0) ? pk(z4[1], z4[0]) : 0u;
      bz.u[1] = (g == 0) ? pk(z4[3], z4[2]) : 0u;
      bz.u[2] = (g == 0) ? 0x00003F80u : 0u;
      bz.u[3] = 0u;
      const u16* ab = (g == 0) ? (sAp + nq * 1024 + m * 8) : sZ;
      const int ainc = (g == 0) ? 128 : 0;
      #pragma unroll
      for (int t2 = 0; t2 < 8; ++t2){
        short8 aw = *(const short8*)(ab + t2 * ainc);
        hv[q][t2 >> 1][t2 & 1] =
          __builtin_amdgcn_mfma_f32_16x16x32_bf16(aw, bz.s, hv[q][t2 >> 1][t2 & 1], 0, 0, 0);
      }
    }
    __syncthreads();
    buf ^= 1;
  }

  // ================= phase C: out = h @ W_head + b_head ===================
  // pack h (RNE — pipeline's final h rounding)
  short8 p[4][4];
  #pragma unroll
  for (int q = 0; q < 4; ++q)
    #pragma unroll
    for (int c2 = 0; c2 < 4; ++c2)
      p[q][c2] = mkfrag(hv[q][c2][0], hv[q][c2][1]);

  f32x4 acc[4][8];
  #pragma unroll
  for (int q = 0; q < 4; ++q)
    #pragma unroll
    for (int of = 0; of < 8; ++of) acc[q][of] = (f32x4)0.f;

  // prologue: broadcast chunk 0, stage tile 1 (tile 0 staged at mid d==7)
  if (nq == 0){
    #pragma unroll
    for (int q = 0; q < 4; ++q)
      *(short8*)(LT + HXo + rh * 4096 + (q * 64 + m * 4 + g) * 16) = p[q][0];
  }
  stageA(Wt_hd3, 1, LT + 32768);
  __syncthreads();

  // Body c: stage(c+2)[4] ; hx-write (c+1 owner, ds) ; reads tb[c%3] + hx ;
  // CBAR. Steady K=4 keeps stage(c+2), drains stage(c+1). c=14: K=0 drains
  // stage(15). c=15: no barrier.
  #pragma unroll
  for (int c = 0; c < 16; ++c){
    if (c < 14) stageA(Wt_hd3, c + 2, LT + ((c + 2) % 3) * 32768);
    if (c < 15 && nq == ((c + 1) >> 2)){
      #pragma unroll
      for (int q = 0; q < 4; ++q)
        *(short8*)(LT + HXo + ((c + 1) & 1) * 8192 + rh * 4096 + (q * 64 + m * 4 + g) * 16)
          = p[q][(c + 1) & 3];
    }
    const char* hxb = LT + HXo + (c & 1) * 8192 + rh * 4096 + (m * 4 + g) * 16;
    short8 bh[4];
    #pragma unroll
    for (int q = 0; q < 4; ++q) bh[q] = *(const short8*)(hxb + q * 1024);
    const char* wb = LT + (c % 3) * 32768 + nq * 8192 + afoff;
    #pragma unroll
    for (int of = 0; of < 8; ++of){
      short8 aw = *(const short8*)(wb + of * 1024);
      #pragma unroll
      for (int q = 0; q < 4; ++q)
        acc[q][of] = __builtin_amdgcn_mfma_f32_16x16x32_bf16(aw, bh[q], acc[q][of], 0, 0, 0);
    }
    if (c < 14)       CBAR(4);
    else if (c == 14) CBAR(0);
  }

  // epilogue: +bias, store
  #pragma unroll
  for (int q = 0; q < 4; ++q)
    #pragma unroll
    for (int of = 0; of < 8; ++of){
      f32x4 bhd = *(const f32x4*)(b_head + nq * 128 + of * 16 + g * 4);
      f32x4 v;
      #pragma unroll
      for (int r = 0; r < 4; ++r) v[r] = acc[q][of][r] + bhd[r];
      *(f32x4*)(out + (rowbase + q * 16 + m) * 512 + nq * 128 + of * 16 + g * 4) = v;
    }
}

// ---------------------------------------------------------------------------
extern "C" void kernel_launch(void* const* d_in, const int* in_sizes, int n_in,
                              void* d_out, int out_size, void* d_ws, size_t ws_size,
                              hipStream_t stream)
{
  const float* x      = (const float*)d_in[0];
  const float* W_in   = (const float*)d_in[1];
  const float* b_in   = (const float*)d_in[2];
  const float* ln_g   = (const float*)d_in[3];
  const float* ln_b   = (const float*)d_in[4];
  const float* W1     = (const float*)d_in[5];
  const float* b1     = (const float*)d_in[6];
  const float* W2     = (const float*)d_in[7];
  const float* b2     = (const float*)d_in[8];
  const float* W_head = (const float*)d_in[9];
  const float* b_head = (const float*)d_in[10];
  float* out = (float*)d_out;
  const int B = in_sizes[0] / 512;

  char* ws = (char*)d_ws;
  u16*   Wt_in3 = (u16*)ws;                 // 262144
  u16*   Wt_hd3 = Wt_in3 + 262144;          // 262144
  u16*   gw1f   = Wt_hd3 + 262144;          // 20480
  u16*   updA   = gw1f + 20480;             // 32768
  float* Up     = (float*)(updA + 32768);   // 32
  float* Vp     = Up + 32;                  // 32

  prep_k<<<2256, 256, 0, stream>>>(W_in, W_head, ln_g, W1, W2, b2, Wt_in3, Wt_hd3, gw1f, updA);
  uv_k<<<32, 64, 0, stream>>>(ln_g, ln_b, W1, b1, Up, Vp);
  fused_k<<<B / 128, 512, 0, stream>>>(x, Wt_in3, b_in, Wt_hd3, b_head, gw1f, updA, Up, Vp, out);
}